// Round 5
// baseline (6470.467 us; speedup 1.0000x reference)
//
#include <hip/hip_runtime.h>

typedef __bf16 bf16_t;
typedef __bf16 bf16x8 __attribute__((ext_vector_type(8)));
typedef __bf16 bf16x4 __attribute__((ext_vector_type(4)));
typedef float  f32x4  __attribute__((ext_vector_type(4)));
typedef unsigned long long u64;

#define S_LEN 512
#define BATCH 64
#define HID 1024
#define BH (BATCH*HID)          /* 65536 */
#define G4 (4*HID)
#define NBLK 256                /* 128 layer-0 + 128 layer-1, 1 block/CU */
#define LBLK 128                /* blocks per layer */
#define NTHR 512                /* 8 waves: 4 M-tiles x 2 K-halves */
#define CSTRIDE 32              /* done-word spacing: 128 B */

__device__ __forceinline__ float sigmoid_f(float x) { return 1.f / (1.f + __expf(-x)); }
__device__ __forceinline__ float tanh_f(float x) {
    float e = __expf(-2.f * fabsf(x));
    float t = (1.f - e) / (1.f + e);
    return x >= 0.f ? t : -t;
}

__device__ __forceinline__ bf16x8 cvt8(const float* p) {
    float4 a = *reinterpret_cast<const float4*>(p);
    float4 b = *reinterpret_cast<const float4*>(p + 4);
    bf16x8 r;
    r[0] = (bf16_t)a.x; r[1] = (bf16_t)a.y; r[2] = (bf16_t)a.z; r[3] = (bf16_t)a.w;
    r[4] = (bf16_t)b.x; r[5] = (bf16_t)b.y; r[6] = (bf16_t)b.z; r[7] = (bf16_t)b.w;
    return r;
}

// Wave-wide wait on one chunk: 16 lanes poll the chunk's 16 producer done-words
// (done[blk] = last published step + 1; single writer, plain store, no RMW).
// 16 distinct cache lines -> no hot-bank serialization.
__device__ __forceinline__ void wait_words(const unsigned* dw, int cc, unsigned thr, int lane) {
    const unsigned* p = dw + (size_t)(16 * cc + (lane & 15)) * CSTRIDE;
    for (;;) {
        unsigned v = thr;
        if (lane < 16)
            v = __hip_atomic_load(p, __ATOMIC_RELAXED, __HIP_MEMORY_SCOPE_AGENT);
        if (__all((int)(v >= thr))) break;
        __builtin_amdgcn_s_sleep(1);
    }
    asm volatile("" ::: "memory");   // don't hoist data loads above the poll
}

// Chunk-streamed half-GEMM (one operand phase, K=512 for this wave's K-half).
// Chunks of 128 K gated by producer done-words; 1-deep load pipeline.
__device__ __forceinline__ void gemm_phase_chunked(
    const bf16_t* __restrict__ abase, const unsigned* __restrict__ dwords, unsigned thr,
    int grbase, const unsigned char* __restrict__ lds_w,
    int kh, int quad, int r16, int lane, int ff, f32x4& acc0, f32x4& acc1)
{
    bf16x8 af[8];
    wait_words(dwords, 4 * kh, thr, lane);
    if (!ff) __builtin_amdgcn_fence(__ATOMIC_ACQUIRE, "agent");   // ring fallback only
    #pragma unroll
    for (int j = 0; j < 4; ++j)
        af[j] = *reinterpret_cast<const bf16x8*>(abase + j * 32);
    #pragma unroll
    for (int c = 0; c < 4; ++c) {
        if (c < 3) {
            wait_words(dwords, 4 * kh + c + 1, thr, lane);
            if (!ff) __builtin_amdgcn_fence(__ATOMIC_ACQUIRE, "agent");
            #pragma unroll
            for (int j = 0; j < 4; ++j)
                af[((c + 1) & 1) * 4 + j] =
                    *reinterpret_cast<const bf16x8*>(abase + (4 * (c + 1) + j) * 32);
        }
        #pragma unroll
        for (int j = 0; j < 4; ++j) {
            int ks = 4 * c + j;
            int gr = grbase + kh * 64 + ks * 4 + quad;
            bf16x8 b0 = *reinterpret_cast<const bf16x8*>(&lds_w[gr * 512 + r16 * 16]);
            bf16x8 b1 = *reinterpret_cast<const bf16x8*>(&lds_w[gr * 512 + (16 + r16) * 16]);
            acc0 = __builtin_amdgcn_mfma_f32_16x16x32_bf16(af[(c & 1) * 4 + j], b0, acc0, 0, 0, 0);
            acc1 = __builtin_amdgcn_mfma_f32_16x16x32_bf16(af[(c & 1) * 4 + j], b1, acc1, 0, 0, 0);
        }
    }
}

// prep: zero done-words, prefill bf16 h-buffers (t = -1 slot = mask).
__global__ void prep_kernel(const float* __restrict__ h0,
                            bf16_t* __restrict__ h0buf, bf16_t* __restrict__ h1buf,
                            unsigned* __restrict__ dw, int mask0, int mask1) {
    int gtid = blockIdx.x * blockDim.x + threadIdx.x;
    int gsz  = gridDim.x * blockDim.x;
    if (gtid < 2 * LBLK) dw[gtid * CSTRIDE] = 0u;
    for (int i = gtid; i < BH; i += gsz) {
        h0buf[(size_t)mask0 * BH + i] = (bf16_t)h0[i];
        h1buf[(size_t)mask1 * BH + i] = (bf16_t)h0[BH + i];
    }
}

// Persistent pipelined LSTM, producer-granular done-word dataflow.
// Block b: layer l=b>>7, unit-group ug8=b&127 (8 hidden units -> 32 gate rows).
// LDS weights: [256 granules][32 rows] bf16x8 = 128 KB (0-127 Wx, 128-255 Wh).
// Waves: wv = 2*mt + kh; mt = M-tile (16 batches), kh = K-half.
// done[l*128+blk] = (last step published by blk)+1; single-writer plain agent store
// after vmcnt(0) drain of the h stores. Consumers poll the 16 words of each K-chunk.
__global__ __launch_bounds__(NTHR, 2) void lstm_persistent(
    const float* __restrict__ x,
    const float* __restrict__ c0,
    const float* __restrict__ Wx,
    const float* __restrict__ Wh,
    const float* __restrict__ bx,
    const float* __restrict__ bh,
    float* __restrict__ out,
    bf16_t* __restrict__ h0buf,
    bf16_t* __restrict__ h1buf,
    unsigned* __restrict__ dw,
    int ff, int mask0, int mask1)
{
    __shared__ __attribute__((aligned(16))) unsigned char lds_w[256 * 512];  // 128 KB
    __shared__ __attribute__((aligned(16))) float lds_red[8 * 256];          // 8 KB K-reduce
    __shared__ __attribute__((aligned(16))) float lds_hf[BATCH * 8];         // 2 KB h staging

    const int tid  = threadIdx.x;
    const int bid  = blockIdx.x;
    const int l    = bid >> 7;
    const int ug8  = bid & 127;
    const int lane = tid & 63;
    const int wv   = tid >> 6;
    const int mt   = wv >> 1;
    const int kh   = wv & 1;
    const int quad = lane >> 4;
    const int r16  = lane & 15;

    float* ys   = out;
    float* hfin = out + (size_t)S_LEN * BH;
    float* cfin = hfin + 2 * BH;

    // ---- stage this block's 32 weight rows (fp32 -> bf16) into LDS [gran][row] ----
    {
        const float* WxL = Wx + (size_t)l * G4 * HID;
        const float* WhL = Wh + (size_t)l * G4 * HID;
        for (int ch = tid; ch < 32 * 256; ch += NTHR) {
            int row = ch & 31;           // row = 4*unit_local + gate
            int gr  = ch >> 5;
            int ul = row >> 2, g = row & 3;
            size_t R = (size_t)g * HID + 8 * ug8 + ul;
            const float* src = (gr < 128) ? (WxL + R * HID + (size_t)gr * 8)
                                          : (WhL + R * HID + (size_t)(gr - 128) * 8);
            *reinterpret_cast<bf16x8*>(&lds_w[gr * 512 + row * 16]) = cvt8(src);
        }
    }

    const int b_loc  = lane >> 2;
    const int uu     = lane & 3;
    const int b_glob = 16 * mt + b_loc;
    const int u_loc  = 4 * kh + uu;
    const int u_glob = 8 * ug8 + u_loc;

    float bias_r[4];
    #pragma unroll
    for (int gi = 0; gi < 4; ++gi) {
        int R = gi * HID + u_glob;
        bias_r[gi] = bx[l * G4 + R] + bh[l * G4 + R];
    }
    float c_reg = c0[(size_t)l * BH + (size_t)b_glob * HID + u_glob];

    bf16_t* pubbuf = (l == 0) ? h0buf : h1buf;
    const int pubmask = (l == 0) ? mask0 : mask1;
    const unsigned* dw0 = dw;                       // layer-0 done-words
    const unsigned* dw1 = dw + LBLK * CSTRIDE;      // layer-1 done-words
    unsigned* myword = &dw[(l * LBLK + ug8) * CSTRIDE];
    __syncthreads();

    const int arow_off = (16 * mt + r16) * HID + kh * 512 + quad * 8;

    // L0: prefetch x fragments for t=0 into registers
    bf16x8 axp[16];
    if (l == 0) {
        const float* arow = x + arow_off;
        #pragma unroll
        for (int ks = 0; ks < 16; ++ks) axp[ks] = cvt8(arow + ks * 32);
    }

    for (int t = 0; t < S_LEN; ++t) {
        f32x4 acc0 = {0.f, 0.f, 0.f, 0.f};
        f32x4 acc1 = {0.f, 0.f, 0.f, 0.f};

        if (l == 0) {
            // ---- x-part from prefetched registers (no cross-block dependency) ----
            #pragma unroll
            for (int ks = 0; ks < 16; ++ks) {
                int gr = kh * 64 + ks * 4 + quad;
                bf16x8 b0 = *reinterpret_cast<const bf16x8*>(&lds_w[gr * 512 + r16 * 16]);
                bf16x8 b1 = *reinterpret_cast<const bf16x8*>(&lds_w[gr * 512 + (16 + r16) * 16]);
                acc0 = __builtin_amdgcn_mfma_f32_16x16x32_bf16(axp[ks], b0, acc0, 0, 0, 0);
                acc1 = __builtin_amdgcn_mfma_f32_16x16x32_bf16(axp[ks], b1, acc1, 0, 0, 0);
            }
            // ---- h-part: chunk-streamed from h0buf[t-1] (word >= t: published t-1) ----
            const bf16_t* ah = h0buf + (size_t)((t - 1) & mask0) * BH + arow_off;
            gemm_phase_chunked(ah, dw0, (unsigned)t, 128, lds_w,
                               kh, quad, r16, lane, ff, acc0, acc1);
        } else {
            // ---- h-part FIRST (own layer, ready earliest): h1buf[t-1] ----
            const bf16_t* ah = h1buf + (size_t)((t - 1) & mask1) * BH + arow_off;
            gemm_phase_chunked(ah, dw1, (unsigned)t, 128, lds_w,
                               kh, quad, r16, lane, ff, acc0, acc1);
            // ---- x-part: chunk-streamed from h0buf[t] (word >= t+1: L0 published t) ----
            const bf16_t* ax = h0buf + (size_t)(t & mask0) * BH + arow_off;
            gemm_phase_chunked(ax, dw0, (unsigned)(t + 1), 0, lds_w,
                               kh, quad, r16, lane, ff, acc0, acc1);
        }

        // ---- K-half reduce: wave (mt,kh) keeps N-tile kh, ships the other ----
        {
            f32x4 ship = kh ? acc0 : acc1;
            *reinterpret_cast<f32x4*>(&lds_red[wv * 256 + lane * 4]) = ship;
            __syncthreads();
            f32x4 part = *reinterpret_cast<const f32x4*>(&lds_red[(wv ^ 1) * 256 + lane * 4]);
            f32x4 keep = kh ? acc1 : acc0;
            acc0 = keep + part;
        }

        // ---- gather 4 gates for (b_loc, uu); C layout: col=lane&15, row=quad*4+reg ----
        {
            const int quad_s = b_loc >> 2;
            const int reg_s  = b_loc & 3;
            float gsum[4];
            #pragma unroll
            for (int gi = 0; gi < 4; ++gi) {
                int lane_s = (quad_s << 4) | (4 * uu + gi);
                float v0 = __shfl(acc0[0], lane_s, 64);
                float v1 = __shfl(acc0[1], lane_s, 64);
                float v2 = __shfl(acc0[2], lane_s, 64);
                float v3 = __shfl(acc0[3], lane_s, 64);
                float v  = (reg_s == 0) ? v0 : (reg_s == 1) ? v1 : (reg_s == 2) ? v2 : v3;
                gsum[gi] = v + bias_r[gi];
            }
            float fg = sigmoid_f(gsum[0]);
            float ig = sigmoid_f(gsum[1]);
            float og = sigmoid_f(gsum[2]);
            float cx = tanh_f(gsum[3]);
            float cN = fg * c_reg + ig * cx;
            float h  = og * tanh_f(cN);
            c_reg = cN;
            lds_hf[b_glob * 8 + u_loc] = h;
            if (t == S_LEN - 1) {
                hfin[(size_t)l * BH + (size_t)b_glob * HID + u_glob] = h;
                cfin[(size_t)l * BH + (size_t)b_glob * HID + u_glob] = cN;
            }
        }
        __syncthreads();

        // ---- publish: wave 0 stores 64 batches x 8 units, write-through to LLC ----
        if (tid < 64) {
            // ring fallback: before overwriting slot t&7 (held h0[t-8]), make sure
            // every L1 block consumed it (published >= t-7 -> word >= t-6).
            if (!ff && l == 0 && t >= 8) {
                const unsigned thr = (unsigned)(t - 6);
                for (;;) {
                    unsigned v0 = __hip_atomic_load(&dw1[lane * CSTRIDE],
                                                    __ATOMIC_RELAXED, __HIP_MEMORY_SCOPE_AGENT);
                    unsigned v1 = __hip_atomic_load(&dw1[(64 + lane) * CSTRIDE],
                                                    __ATOMIC_RELAXED, __HIP_MEMORY_SCOPE_AGENT);
                    if (__all((int)(v0 >= thr && v1 >= thr))) break;
                    __builtin_amdgcn_s_sleep(1);
                }
            }
            const float* hp = &lds_hf[lane * 8];
            union { bf16x4 v; u64 q; } p0, p1;
            #pragma unroll
            for (int j = 0; j < 4; ++j) {
                p0.v[j] = (bf16_t)hp[j];
                p1.v[j] = (bf16_t)hp[4 + j];
            }
            bf16_t* dst = pubbuf + (size_t)(t & pubmask) * BH + (size_t)lane * HID + 8 * ug8;
            __hip_atomic_store((u64*)(void*)dst,       p0.q, __ATOMIC_RELAXED, __HIP_MEMORY_SCOPE_AGENT);
            __hip_atomic_store((u64*)(void*)(dst + 4), p1.q, __ATOMIC_RELAXED, __HIP_MEMORY_SCOPE_AGENT);
            asm volatile("s_waitcnt vmcnt(0)" ::: "memory");  // h at LLC before done-word
            if (lane == 0)
                __hip_atomic_store(myword, (unsigned)(t + 1),
                                   __ATOMIC_RELAXED, __HIP_MEMORY_SCOPE_AGENT);
            if (l == 1) {   // fp32 output, off the sync critical path
                float* yd = ys + (size_t)t * BH + (size_t)lane * HID + 8 * ug8;
                __builtin_nontemporal_store(*reinterpret_cast<const f32x4*>(hp),     reinterpret_cast<f32x4*>(yd));
                __builtin_nontemporal_store(*reinterpret_cast<const f32x4*>(hp + 4), reinterpret_cast<f32x4*>(yd + 4));
            }
        }

        // L0: prefetch next step's x fragments (latency hides under next wait)
        if (l == 0 && t + 1 < S_LEN) {
            const float* arow = x + (size_t)(t + 1) * BH + arow_off;
            #pragma unroll
            for (int ks = 0; ks < 16; ++ks) axp[ks] = cvt8(arow + ks * 32);
        }
    }
}

extern "C" void kernel_launch(void* const* d_in, const int* in_sizes, int n_in,
                              void* d_out, int out_size, void* d_ws, size_t ws_size,
                              hipStream_t stream) {
    (void)in_sizes; (void)n_in; (void)out_size;
    const float* x  = (const float*)d_in[0];
    const float* h0 = (const float*)d_in[1];
    const float* c0 = (const float*)d_in[2];
    const float* Wx = (const float*)d_in[3];
    const float* Wh = (const float*)d_in[4];
    const float* bx = (const float*)d_in[5];
    const float* bh = (const float*)d_in[6];

    unsigned char* ws = (unsigned char*)d_ws;
    unsigned* dw = (unsigned*)ws;                        // 256 done-words, 128 B apart (32 KB)
    size_t off = 32768;
    size_t need_ff = off + (size_t)2 * S_LEN * BH * 2;   // two 64 MB h-buffers
    int ff, mask0, mask1;
    bf16_t *h0buf, *h1buf;
    if (ws_size >= need_ff) {
        ff = 1; mask0 = S_LEN - 1; mask1 = S_LEN - 1;    // per-step-unique slots
        h0buf = (bf16_t*)(ws + off); off += (size_t)S_LEN * BH * 2;
        h1buf = (bf16_t*)(ws + off);
    } else {
        ff = 0; mask0 = 7; mask1 = 1;                    // ring + fence fallback
        h0buf = (bf16_t*)(ws + off); off += (size_t)8 * BH * 2;
        h1buf = (bf16_t*)(ws + off);
    }

    prep_kernel<<<2048, 256, 0, stream>>>(h0, h0buf, h1buf, dw, mask0, mask1);
    lstm_persistent<<<NBLK, NTHR, 0, stream>>>(x, c0, Wx, Wh, bx, bh, (float*)d_out,
                                               h0buf, h1buf, dw, ff, mask0, mask1);
}